// Round 8
// baseline (2001.310 us; speedup 1.0000x reference)
//
#include <hip/hip_runtime.h>

// ComplexLSTM: B=32,S=512,I=512,H=512
// ws layout (bytes)
#define OFF_WZT   0ull
#define OFF_WHT   5242880ull
#define OFF_BIAS  10485760ull
#define OFF_XPERM 10496000ull
#define OFF_HBUF  94382080ull   // 4 domains x 2 bufs x 4096 u64 = 262144 B
#define NWG 256

typedef __attribute__((ext_vector_type(8))) short short8;
typedef __attribute__((ext_vector_type(4))) float f32x4;

__device__ __forceinline__ unsigned short f2bf(float f) {
  unsigned int u = __float_as_uint(f);
  u += 0x7fffu + ((u >> 16) & 1u);
  return (unsigned short)(u >> 16);
}
__device__ __forceinline__ float bf2f(unsigned short h) {
  return __uint_as_float(((unsigned int)h) << 16);
}

struct PackArgs {
  const float* zlo[5]; const float* zhi[5];
  const float* hlo[5]; const float* hhi[5];
  const float* bias[5];
};

// WzT[c][k]: k<512 -> z_r coeff (col k), k>=512 -> z_i coeff.
// WhT[c][k]: K interleaved: k=2*kk+ri, ri=0 -> h_r[kk] coeff, ri=1 -> h_i[kk] coeff.
// c = g*512+h (g: 0=i,1=f,2=o,3=cr,4=ci)
__global__ void pack_kernel(PackArgs args, unsigned short* __restrict__ WzT,
                            unsigned short* __restrict__ WhT,
                            float* __restrict__ bias_out,
                            unsigned long long* __restrict__ Hbuf64) {
  const long long total = 2ll * 2621440ll;
  long long stride = (long long)gridDim.x * blockDim.x;
  for (long long gid = (long long)blockIdx.x * blockDim.x + threadIdx.x; gid < total; gid += stride) {
    int sel = (int)(gid >= 2621440ll);
    int e = (int)(gid - (long long)sel * 2621440ll);
    int c = e >> 10, k = e & 1023;
    int g = c >> 9, h = c & 511;
    float v;
    if (sel) { // WhT interleaved
      int kk = k >> 1, ri = k & 1;
      const float* src = ri ? args.hhi[g] : args.hlo[g];
      float sgn = (!ri || g == 4) ? 1.f : -1.f;
      v = sgn * src[kk * 512 + h];
    } else {   // WzT block layout
      int kk = k & 511;
      const float* src = (k < 512) ? args.zlo[g] : args.zhi[g];
      float sgn = (k < 512 || g == 4) ? 1.f : -1.f;
      v = sgn * src[kk * 512 + h];
    }
    (sel ? WhT : WzT)[(long long)c * 1024 + k] = f2bf(v);
  }
  int gid0 = blockIdx.x * blockDim.x + threadIdx.x;
  if (gid0 < 2560) { int g = gid0 >> 9; bias_out[gid0] = args.bias[g][gid0 & 511]; }
  if (gid0 < 32768) Hbuf64[gid0] = 0ull; // clear all tags (replay safety)
}

// Phase 1: X = [z_r|z_i](16384x1024) @ WzT^T + bias -> bf16,
// permuted to [t][wg][b][40] with HIDDEN-MAJOR inner order: idx = jj*5 + g.
__global__ __launch_bounds__(256) void phase1_kernel(
    const float* __restrict__ zr, const float* __restrict__ zi,
    const unsigned short* __restrict__ WzT, const float* __restrict__ bias,
    unsigned short* __restrict__ Xperm) {
  __shared__ unsigned short Al[64 * 40];
  __shared__ unsigned short Bl[64 * 40];
  int bid = blockIdx.x;
  int bm = bid / 40, bn = bid % 40;
  int tid = threadIdx.x;
  int wave = tid >> 6, lane = tid & 63;
  int mq = wave >> 1, nq = wave & 1;
  int lr = lane & 15, lkb = (lane >> 4) * 8;
  int srow = tid >> 2, sq = tid & 3;

  f32x4 acc[2][2];
#pragma unroll
  for (int i0 = 0; i0 < 2; i0++)
#pragma unroll
    for (int j0 = 0; j0 < 2; j0++) acc[i0][j0] = (f32x4){0.f, 0.f, 0.f, 0.f};

  for (int kb = 0; kb < 32; kb++) {
    int gk = kb * 32 + sq * 8;
    const float* srcp = (gk < 512) ? (zr + (long long)(bm * 64 + srow) * 512 + gk)
                                   : (zi + (long long)(bm * 64 + srow) * 512 + (gk - 512));
    float4 f0 = *(const float4*)srcp;
    float4 f1 = *(const float4*)(srcp + 4);
    uint4 p;
    p.x = (unsigned)f2bf(f0.x) | ((unsigned)f2bf(f0.y) << 16);
    p.y = (unsigned)f2bf(f0.z) | ((unsigned)f2bf(f0.w) << 16);
    p.z = (unsigned)f2bf(f1.x) | ((unsigned)f2bf(f1.y) << 16);
    p.w = (unsigned)f2bf(f1.z) | ((unsigned)f2bf(f1.w) << 16);
    *(uint4*)(&Al[srow * 40 + sq * 8]) = p;
    const unsigned short* bsrc = WzT + (long long)(bn * 64 + srow) * 1024 + kb * 32 + sq * 8;
    *(uint4*)(&Bl[srow * 40 + sq * 8]) = *(const uint4*)bsrc;
    __syncthreads();
    short8 a0 = *(const short8*)(&Al[(mq * 32 + 0 + lr) * 40 + lkb]);
    short8 a1 = *(const short8*)(&Al[(mq * 32 + 16 + lr) * 40 + lkb]);
    short8 b0 = *(const short8*)(&Bl[(nq * 32 + 0 + lr) * 40 + lkb]);
    short8 b1 = *(const short8*)(&Bl[(nq * 32 + 16 + lr) * 40 + lkb]);
    acc[0][0] = __builtin_amdgcn_mfma_f32_16x16x32_bf16(a0, b0, acc[0][0], 0, 0, 0);
    acc[0][1] = __builtin_amdgcn_mfma_f32_16x16x32_bf16(a0, b1, acc[0][1], 0, 0, 0);
    acc[1][0] = __builtin_amdgcn_mfma_f32_16x16x32_bf16(a1, b0, acc[1][0], 0, 0, 0);
    acc[1][1] = __builtin_amdgcn_mfma_f32_16x16x32_bf16(a1, b1, acc[1][1], 0, 0, 0);
    __syncthreads();
  }
#pragma unroll
  for (int mt = 0; mt < 2; mt++)
#pragma unroll
    for (int nt = 0; nt < 2; nt++) {
      int C = bn * 64 + nq * 32 + nt * 16 + lr;
      float bv = bias[C];
      int g = C >> 9, h = C & 511;
      int wgc = h >> 3, jj = h & 7;
#pragma unroll
      for (int r = 0; r < 4; r++) {
        int R = bm * 64 + mq * 32 + mt * 16 + (lane >> 4) * 4 + r;
        int bb = R >> 9, tt = R & 511;
        float v = acc[mt][nt][r] + bv;
        Xperm[(((long long)(tt * 64 + wgc)) * 32 + bb) * 40 + jj * 5 + g] = f2bf(v);
      }
    }
}

// Phase 2: 4 sync domains (8 batch rows each) x 64 WGs, 512 threads (8 waves).
// Waves 0-3: compute. Wave nt owns hidden cols {wl*8+2nt, wl*8+2nt+1}: full-K
// GEMM (B in registers, cols cw = hj*5+g, cw>=10 garbage/unused), within-wave
// gate gather via per-wave LDS scratch (no barrier), elementwise, tagged store.
// Waves 4-7: poll 16 chunks/thread + stage into Hl. ONE barrier per step.
// h-broadcast: tagged u64 chunks (tag=t+1)<<32 | (bf16 hr | hi<<16);
// chunk c for (row r, col j): c = ((j>>2)*8 + r)*4 + (j&3) (fragment-major).
__global__ __launch_bounds__(512, 2) void recur_kernel(
    const unsigned short* __restrict__ WhT,
    const unsigned short* __restrict__ Xperm,
    unsigned long long* __restrict__ Hbuf64,
    float* __restrict__ out) {
  extern __shared__ char ldsraw[];
  unsigned int* Hl32 = (unsigned int*)ldsraw;        // 8192 u32 (32 KB), frag-major
  float* gatesLds = (float*)(ldsraw + 32768);        // 4 waves x 256 f32 (4 KB)

  int bid = blockIdx.x;
  int d = bid >> 6, wl = bid & 63;
  int tid = threadIdx.x;
  int wave = tid >> 6, lane = tid & 63;
  int lr = lane & 15, kq = lane >> 4;
  int nt = wave;                         // compute waves only (wave<4)

  // --- init: B fragments straight from global into registers (compute waves) ---
  short8 breg[32];
  if (wave < 4) {
    int g = lr % 5;
    int hj2 = (lr >= 5) ? 1 : 0;         // lr>=10 duplicates hj=1 (cols unused)
    int gcol = g * 512 + wl * 8 + nt * 2 + hj2;
    const unsigned short* wsrc = WhT + (long long)gcol * 1024 + kq * 8;
#pragma unroll
    for (int kk = 0; kk < 32; kk++)
      breg[kk] = *(const short8*)(wsrc + kk * 32);
  }
  // zero Hl (rows 8-15 of each fragment group stay zero forever -> M=8 padding)
  {
    uint4 z = {0u, 0u, 0u, 0u};
#pragma unroll
    for (int i = 0; i < 4; i++) ((uint4*)Hl32)[tid + i * 512] = z;
  }

  unsigned long long* Hme = Hbuf64 + d * 8192;
  float c_r = 0.f, c_i = 0.f;
  int hj = lane >> 3, r = lane & 7;      // elementwise target when lane<16 (compute)
  int pt = tid - 256;                    // poll thread index (waves 4-7)

  for (int t = 0; t < 512; t++) {
    if (wave < 4) {
      float xg[5];
      if (lane < 16) { // issue Xperm loads early; latency hides in B1 wait
        const unsigned short* xp =
            Xperm + (((long long)(t * 64 + wl)) * 32 + (8 * d + r)) * 40 + (nt * 2 + hj) * 5;
#pragma unroll
        for (int g = 0; g < 5; g++) xg[g] = bf2f(xp[g]);
      }
      __syncthreads(); // B1: h(t-1) staged, Hl ready

      f32x4 acc[4];
#pragma unroll
      for (int q = 0; q < 4; q++) acc[q] = (f32x4){0.f, 0.f, 0.f, 0.f};
      const unsigned short* Hls = (const unsigned short*)Hl32;
#pragma unroll
      for (int kk = 0; kk < 32; kk++) {
        short8 a = *(const short8*)(Hls + (kk * 4 + kq) * 128 + lr * 8);
        acc[kk & 3] = __builtin_amdgcn_mfma_f32_16x16x32_bf16(a, breg[kk], acc[kk & 3], 0, 0, 0);
      }
      f32x4 as = (acc[0] + acc[1]) + (acc[2] + acc[3]);

      // within-wave gate gather through per-wave LDS scratch (lgkmcnt-ordered)
      float* gb = gatesLds + wave * 256;
#pragma unroll
      for (int q = 0; q < 4; q++) gb[q * 64 + lane] = as[q];

      if (lane < 16) {
        int q = lane & 3, s = (lane & 7) >> 2;
        float gv[5];
#pragma unroll
        for (int g = 0; g < 5; g++)
          gv[g] = gb[q * 64 + (hj * 5 + g + 16 * s)] + xg[g];
        float ig = 1.f / (1.f + __expf(-gv[0]));
        float fg = 1.f / (1.f + __expf(-gv[1]));
        float og = 1.f / (1.f + __expf(-gv[2]));
        float crp = gv[3], cip = gv[4];
        float mag = fmaxf(sqrtf(crp * crp + cip * cip + 1e-14f), 1e-8f);
        float e1 = __expf(-2.f * mag);
        float s1 = (1.f - e1) * __frcp_rn((1.f + e1) * mag);
        c_r = fg * c_r + ig * (crp * s1);
        c_i = fg * c_i + ig * (cip * s1);
        float mag2 = fmaxf(sqrtf(c_r * c_r + c_i * c_i + 1e-14f), 1e-8f);
        float e2 = __expf(-2.f * mag2);
        float s2 = (1.f - e2) * __frcp_rn((1.f + e2) * mag2);
        float hr = og * (c_r * s2);
        float hi = og * (c_i * s2);
        // tagged broadcast chunk (single atomic u64; protocol orders everything)
        int j = wl * 8 + nt * 2 + hj;
        int cidx = ((j >> 2) * 8 + r) * 4 + (j & 3);
        unsigned hv = (unsigned)f2bf(hr) | ((unsigned)f2bf(hi) << 16);
        __hip_atomic_store(Hme + (t & 1) * 4096 + cidx,
                           ((unsigned long long)(t + 1) << 32) | hv,
                           __ATOMIC_RELAXED, __HIP_MEMORY_SCOPE_AGENT);
        // shadow HBM output stores
        int b = 8 * d + r;
        out[(long long)b * 262144 + t * 512 + j] = hr;
        out[8388608ll + (long long)b * 262144 + t * 512 + j] = hi;
        if (t == 511) {
          out[16777216ll + b * 512 + j] = hr;
          out[16793600ll + b * 512 + j] = hi;
          out[16809984ll + b * 512 + j] = c_r;
          out[16826368ll + b * 512 + j] = c_i;
        }
      }
    } else {
      // poll waves: detect h(t-1) chunks, stage into Hl, then barrier
      if (t > 0) {
        const unsigned long long* hb = Hme + ((t - 1) & 1) * 4096;
        unsigned long long v[16];
        unsigned got = 0;
        while (true) {
#pragma unroll
          for (int p = 0; p < 16; p++)
            if (!(got & (1u << p)))
              v[p] = __hip_atomic_load(hb + pt + p * 256, __ATOMIC_RELAXED,
                                       __HIP_MEMORY_SCOPE_AGENT);
          unsigned g2 = got;
#pragma unroll
          for (int p = 0; p < 16; p++)
            if (!(got & (1u << p)) && (unsigned)(v[p] >> 32) == (unsigned)t)
              g2 |= 1u << p;
          got = g2;
          if (got == 0xFFFFu) break;
          __builtin_amdgcn_s_sleep(1);
        }
#pragma unroll
        for (int p = 0; p < 16; p++) {
          int c = pt + p * 256;
          Hl32[((c >> 5) * 16 + ((c >> 2) & 7)) * 4 + (c & 3)] = (unsigned)v[p];
        }
      }
      __syncthreads(); // B1
    }
  }
}

extern "C" void kernel_launch(void* const* d_in, const int* in_sizes, int n_in,
                              void* d_out, int out_size, void* d_ws, size_t ws_size,
                              hipStream_t stream) {
  const float* zr = (const float*)d_in[0];
  const float* zi = (const float*)d_in[1];
  // input group bases: i=2, f=8, c=14, o=20; within: WzR,WzI,WhR,WhI,bR,bI
  const int gi = 2, gf = 8, gc = 14, go = 20;
  PackArgs pa;
  const int gbase[5] = {gi, gf, go, gc, gc}; // internal g: 0=i,1=f,2=o,3=cr,4=ci
  for (int g = 0; g < 5; g++) {
    int b = gbase[g];
    if (g < 4) {
      pa.zlo[g] = (const float*)d_in[b + 0];
      pa.zhi[g] = (const float*)d_in[b + 1];
      pa.hlo[g] = (const float*)d_in[b + 2];
      pa.hhi[g] = (const float*)d_in[b + 3];
    } else { // ci: "lo" (real-mult) uses imag weight (+), "hi" (imag-mult) uses real weight (+)
      pa.zlo[g] = (const float*)d_in[b + 1];
      pa.zhi[g] = (const float*)d_in[b + 0];
      pa.hlo[g] = (const float*)d_in[b + 3];
      pa.hhi[g] = (const float*)d_in[b + 2];
    }
  }
  pa.bias[0] = (const float*)d_in[gi + 4];
  pa.bias[1] = (const float*)d_in[gf + 4];
  pa.bias[2] = (const float*)d_in[go + 4];
  pa.bias[3] = (const float*)d_in[gc + 4];
  pa.bias[4] = (const float*)d_in[gc + 5];

  char* ws = (char*)d_ws;
  unsigned short* WzT = (unsigned short*)(ws + OFF_WZT);
  unsigned short* WhT = (unsigned short*)(ws + OFF_WHT);
  float* bias = (float*)(ws + OFF_BIAS);
  unsigned short* Xperm = (unsigned short*)(ws + OFF_XPERM);
  unsigned long long* Hbuf64 = (unsigned long long*)(ws + OFF_HBUF);

  pack_kernel<<<2048, 256, 0, stream>>>(pa, WzT, WhT, bias, Hbuf64);
  phase1_kernel<<<10240, 256, 0, stream>>>(zr, zi, WzT, bias, Xperm);

  const int ldsBytes = 81920; // 36864 used; oversized to force 1 WG/CU
  (void)hipFuncSetAttribute((const void*)recur_kernel,
                            hipFuncAttributeMaxDynamicSharedMemorySize, ldsBytes);
  recur_kernel<<<NWG, 512, ldsBytes, stream>>>(WhT, Xperm, Hbuf64, (float*)d_out);
}